// Round 4
// baseline (678.221 us; speedup 1.0000x reference)
//
#include <hip/hip_runtime.h>

#define BB 8
#define NN 16384
#define CC 256
#define DD 32
#define EPSF 1e-6f

// ws layout (float units)
#define QBUF_FLOATS (2ull*BB*NN*DD)            // 32 MiB of normalized Q
#define ACC_STRIDE 8480                         // per (s,b): KX[32][256], xsum[256], ksum0[32]
#define ACC_OFF QBUF_FLOATS
#define ACC_FLOATS (16*ACC_STRIDE)
#define FIN_OFF (ACC_OFF + ACC_FLOATS)
#define FIN_STRIDE 8480
#define WBF_OFF (FIN_OFF + 16*FIN_STRIDE)       // 32768 ushort = 16384 floats

typedef __attribute__((ext_vector_type(8))) short bh8;
typedef __attribute__((ext_vector_type(4))) float f4;
typedef __attribute__((ext_vector_type(2))) unsigned int u32x2;

__device__ __forceinline__ unsigned int bfp(float f) {
    unsigned int u = __float_as_uint(f);
    return (u + 0x7FFFu + ((u >> 16) & 1u)) >> 16;   // RNE fp32->bf16 bits
}

// ---------------------------------------------------------------------------
// k0: convert the 4 projection weight matrices to bf16 once.
// ---------------------------------------------------------------------------
__global__ __launch_bounds__(256)
void k0_cvt(const float* __restrict__ Wk, const float* __restrict__ Wq,
            const float* __restrict__ Wky, const float* __restrict__ Wqy,
            unsigned short* __restrict__ wbf)
{
    int i = blockIdx.x * 256 + threadIdx.x;      // 0..32767
    const float* p = (i < 8192) ? Wk : (i < 16384) ? Wq : (i < 24576) ? Wky : Wqy;
    wbf[i] = (unsigned short)bfp(p[i & 8191]);
}

// ---------------------------------------------------------------------------
// k1: X staged ONCE into LDS in [4p x 16c]-subtiled bf16 layout.
//   byte(p,c) = ((p>>2)*16 + (c>>4))*128 + (p&3)*32 + (c&15)*2   (^ quad-parity<<4)
//   GEMM1 (X.W^T): A-frags contiguous b128.  Norms via shfl.  K -> Ksb bf16.
//   GEMM2 (K.X):  B-frags via ds_read_b64_tr_b16; each lane supplies its OWN
//   8-byte slot address R + (l&15)*8 within the 128B subtile (HW transposes
//   the union region; uniform/partial addresses do NOT work).
// ---------------------------------------------------------------------------
__global__ __launch_bounds__(256, 4)
void k1_proj(const float* __restrict__ x, const float* __restrict__ y,
             const unsigned short* __restrict__ wbf,
             const float* __restrict__ bk, const float* __restrict__ bq,
             const float* __restrict__ bky, const float* __restrict__ bqy,
             float* __restrict__ qbuf, float* __restrict__ acc)
{
    const int b = blockIdx.y, s = blockIdx.z;
    const float* __restrict__ src = (s ? y : x) + (size_t)b * NN * CC;
    const unsigned short* __restrict__ wk = wbf + (s ? 2 : 0) * 8192;
    const unsigned short* __restrict__ wq = wbf + (s ? 3 : 1) * 8192;
    const float* __restrict__ bkp = s ? bky : bk;
    const float* __restrict__ bqp = s ? bqy : bq;
    float* __restrict__ qb = qbuf + (size_t)(s*BB + b) * NN * DD;
    float* __restrict__ accsb = acc + (size_t)(s*BB + b) * ACC_STRIDE;

    __shared__ unsigned short Xsub[16384];   // 32 KB subtiled bf16 X
    __shared__ unsigned short Ksb[32][80];   // 5 KB normalized K [d][p]
    __shared__ float red[4][32];

    const int tid = threadIdx.x;
    const int w = tid >> 6, lane = tid & 63;
    const int l15 = lane & 15, l4 = lane >> 4;
    const int oct = lane & 31, lv = lane >> 5;

    // staging precompute: thread covers rows p = 8*it + prow_lo, cols oct*8..+7
    const int prow_lo = 2 * w + lv;                         // 0..7
    const int hv = (prow_lo >> 2) & 1;                      // quad parity of p
    const int wbyte = (hv * 2048 + (oct >> 1) * 128 + (prow_lo & 3) * 32 + (oct & 1) * 16) ^ (hv << 4);
    // GEMM1 A-frag: p = 16w + l15, c = 32ks + 8l4
    const int pA = 16 * w + l15;
    const int aquad = pA >> 2;
    const int abyte0 = ((aquad * 2048 + (pA & 3) * 32 + (l4 & 1) * 16) ^ ((aquad & 1) << 4))
                       + (l4 >> 1) * 128;                   // + ks*256
    // GEMM2 B-frag tr-read: per-lane 8B slot within the 128B subtile
    const unsigned xsub_lds = (unsigned)(uintptr_t)&Xsub[0];
    const unsigned bbyte0 = xsub_lds + (unsigned)((2 * l4) * 2048 + (4 * w) * 128 + l15 * 8);

    const float biasv[4] = { bkp[l15], bkp[16 + l15], bqp[l15], bqp[16 + l15] };

    f4 g2acc[2][4];
    #pragma unroll
    for (int dt = 0; dt < 2; ++dt)
        #pragma unroll
        for (int ct = 0; ct < 4; ++ct) g2acc[dt][ct] = (f4){0.f, 0.f, 0.f, 0.f};
    float kacc0 = 0.f, kacc1 = 0.f;
    float xs[8];
    #pragma unroll
    for (int j = 0; j < 8; ++j) xs[j] = 0.f;

    for (int ch = 0; ch < 4; ++ch) {
        const int p0 = (blockIdx.x * 4 + ch) * 64;

        // ---- stage X chunk -> subtiled bf16 LDS (coalesced row-pair loads)
        #pragma unroll
        for (int it = 0; it < 8; ++it) {
            const float* gp = src + (size_t)(p0 + 8 * it + prow_lo) * CC + oct * 8;
            float4 va = *(const float4*)gp;
            float4 vb = *(const float4*)(gp + 4);
            xs[0] += va.x; xs[1] += va.y; xs[2] += va.z; xs[3] += va.w;
            xs[4] += vb.x; xs[5] += vb.y; xs[6] += vb.z; xs[7] += vb.w;
            uint4 pk;
            pk.x = bfp(va.x) | (bfp(va.y) << 16);
            pk.y = bfp(va.z) | (bfp(va.w) << 16);
            pk.z = bfp(vb.x) | (bfp(vb.y) << 16);
            pk.w = bfp(vb.z) | (bfp(vb.w) << 16);
            *(uint4*)((char*)Xsub + wbyte + it * 4096) = pk;
        }
        __syncthreads();

        // ---- GEMM1: D[p][d] = X.W^T + bias
        f4 a1[4];
        #pragma unroll
        for (int dt = 0; dt < 4; ++dt)
            a1[dt] = (f4){biasv[dt], biasv[dt], biasv[dt], biasv[dt]};
        #pragma unroll
        for (int ks = 0; ks < 8; ++ks) {
            bh8 xa = *(const bh8*)((const char*)Xsub + abyte0 + ks * 256);
            bh8 w0 = *(const bh8*)(wk + (size_t)(l15) * 256 + 32 * ks + 8 * l4);
            bh8 w1 = *(const bh8*)(wk + (size_t)(16 + l15) * 256 + 32 * ks + 8 * l4);
            bh8 w2 = *(const bh8*)(wq + (size_t)(l15) * 256 + 32 * ks + 8 * l4);
            bh8 w3 = *(const bh8*)(wq + (size_t)(16 + l15) * 256 + 32 * ks + 8 * l4);
            a1[0] = __builtin_amdgcn_mfma_f32_16x16x32_bf16(xa, w0, a1[0], 0, 0, 0);
            a1[1] = __builtin_amdgcn_mfma_f32_16x16x32_bf16(xa, w1, a1[1], 0, 0, 0);
            a1[2] = __builtin_amdgcn_mfma_f32_16x16x32_bf16(xa, w2, a1[2], 0, 0, 0);
            a1[3] = __builtin_amdgcn_mfma_f32_16x16x32_bf16(xa, w3, a1[3], 0, 0, 0);
        }

        // ---- norms (sum over d: shfl across l15 lanes)
        float ssK[4], ssQ[4];
        #pragma unroll
        for (int r = 0; r < 4; ++r) {
            ssK[r] = a1[0][r] * a1[0][r] + a1[1][r] * a1[1][r];
            ssQ[r] = a1[2][r] * a1[2][r] + a1[3][r] * a1[3][r];
        }
        #pragma unroll
        for (int off = 1; off < 16; off <<= 1) {
            #pragma unroll
            for (int r = 0; r < 4; ++r) {
                ssK[r] += __shfl_xor(ssK[r], off);
                ssQ[r] += __shfl_xor(ssQ[r], off);
            }
        }
        float nK[4], nQ[4];
        #pragma unroll
        for (int r = 0; r < 4; ++r) { nK[r] = rsqrtf(ssK[r]); nQ[r] = rsqrtf(ssQ[r]); }

        // ---- normalized K -> Ksb[d][p] bf16
        #pragma unroll
        for (int dt = 0; dt < 2; ++dt) {
            unsigned int lo = bfp(a1[dt][0] * nK[0]) | (bfp(a1[dt][1] * nK[1]) << 16);
            unsigned int hi = bfp(a1[dt][2] * nK[2]) | (bfp(a1[dt][3] * nK[3]) << 16);
            *(uint2*)((char*)Ksb + (16 * dt + l15) * 160 + 32 * w + 8 * l4) = make_uint2(lo, hi);
        }
        kacc0 += a1[0][0]*nK[0] + a1[0][1]*nK[1] + a1[0][2]*nK[2] + a1[0][3]*nK[3];
        kacc1 += a1[1][0]*nK[0] + a1[1][1]*nK[1] + a1[1][2]*nK[2] + a1[1][3]*nK[3];
        // ---- normalized Q -> global fp32
        #pragma unroll
        for (int dt = 2; dt < 4; ++dt)
            #pragma unroll
            for (int r = 0; r < 4; ++r)
                qb[(size_t)(p0 + 16 * w + 4 * l4 + r) * DD + 16 * (dt - 2) + l15] =
                    a1[dt][r] * nQ[r];
        __syncthreads();

        // ---- GEMM2: KX[d][c] += K.X  (B-frags via HW transpose read)
        #pragma unroll
        for (int ks2 = 0; ks2 < 2; ++ks2) {
            bh8 af0 = *(const bh8*)((const char*)Ksb + l15 * 160 + 64 * ks2 + 16 * l4);
            bh8 af1 = *(const bh8*)((const char*)Ksb + (16 + l15) * 160 + 64 * ks2 + 16 * l4);
            u32x2 t0[4], t1[4];
            #pragma unroll
            for (int ct = 0; ct < 4; ++ct) {
                unsigned ad0 = bbyte0 + (unsigned)(ks2 * 16384 + ct * 128);
                unsigned ad1 = (ad0 + 2048u) ^ 16u;
                asm volatile("ds_read_b64_tr_b16 %0, %1" : "=v"(t0[ct]) : "v"(ad0));
                asm volatile("ds_read_b64_tr_b16 %0, %1" : "=v"(t1[ct]) : "v"(ad1));
            }
            asm volatile("s_waitcnt lgkmcnt(0)" ::: "memory");
            __builtin_amdgcn_sched_barrier(0);
            #pragma unroll
            for (int ct = 0; ct < 4; ++ct) {
                union { unsigned int u[4]; bh8 v; } bu;
                bu.u[0] = t0[ct][0]; bu.u[1] = t0[ct][1];
                bu.u[2] = t1[ct][0]; bu.u[3] = t1[ct][1];
                g2acc[0][ct] = __builtin_amdgcn_mfma_f32_16x16x32_bf16(af0, bu.v, g2acc[0][ct], 0, 0, 0);
                g2acc[1][ct] = __builtin_amdgcn_mfma_f32_16x16x32_bf16(af1, bu.v, g2acc[1][ct], 0, 0, 0);
            }
        }
        __syncthreads();
    }

    // ---- epilogue: reductions + atomics
    kacc0 += __shfl_xor(kacc0, 16); kacc0 += __shfl_xor(kacc0, 32);
    kacc1 += __shfl_xor(kacc1, 16); kacc1 += __shfl_xor(kacc1, 32);
    if (lane < 16) { red[w][l15] = kacc0; red[w][16 + l15] = kacc1; }
    #pragma unroll
    for (int j = 0; j < 8; ++j)
        atomicAdd(accsb + 8192 + oct * 8 + j, xs[j]);
    __syncthreads();
    if (tid < 32)
        atomicAdd(accsb + 8448 + tid, red[0][tid] + red[1][tid] + red[2][tid] + red[3][tid]);
    #pragma unroll
    for (int dt = 0; dt < 2; ++dt)
        #pragma unroll
        for (int ct = 0; ct < 4; ++ct)
            #pragma unroll
            for (int r = 0; r < 4; ++r)
                atomicAdd(accsb + (size_t)(16 * dt + 4 * l4 + r) * 256 + 64 * w + 16 * ct + l15,
                          g2acc[dt][ct][r]);
}

// ---------------------------------------------------------------------------
// Kernel 2: finalize per (b,s): mat = KX @ Wv^T + ksum0 (x) bv ; vsum = Wv@xsum + N*bv
// ---------------------------------------------------------------------------
__global__ __launch_bounds__(256, 2)
void k2_finalize(const float* __restrict__ Wv, const float* __restrict__ bv,
                 const float* __restrict__ Wvy, const float* __restrict__ bvy,
                 const float* __restrict__ acc, float* __restrict__ fin)
{
    const int b = blockIdx.x, s = blockIdx.y;
    const float* __restrict__ Wv_ = s ? Wvy : Wv;
    const float* __restrict__ bv_ = s ? bvy : bv;
    const float* __restrict__ a = acc + (size_t)(s*BB + b) * ACC_STRIDE;
    float* __restrict__ f = fin + (size_t)(s*BB + b) * FIN_STRIDE;

    __shared__ float KXt[256][36];
    __shared__ float xsh[256];
    __shared__ float ks0[32];

    const int tid = threadIdx.x;
    for (int d = 0; d < 32; ++d) KXt[tid][d] = a[d*256 + tid];
    xsh[tid] = a[8192 + tid];
    if (tid < 32) { float v = a[8448 + tid]; ks0[tid] = v; f[8448 + tid] = v + EPSF; }
    __syncthreads();

    const int dh = tid >> 7;
    const int c0 = (tid & 127) * 2;
    float macc[16][2];
    #pragma unroll
    for (int i = 0; i < 16; ++i) { macc[i][0]=0.f; macc[i][1]=0.f; }
    float v0 = 0.f, v1 = 0.f;

    for (int k4 = 0; k4 < 256; k4 += 4) {
        float4 wa = *(const float4*)(Wv_ + (size_t)c0*256 + k4);
        float4 wb = *(const float4*)(Wv_ + (size_t)(c0+1)*256 + k4);
        float4 xv = *(const float4*)&xsh[k4];
        v0 += wa.x*xv.x + wa.y*xv.y + wa.z*xv.z + wa.w*xv.w;
        v1 += wb.x*xv.x + wb.y*xv.y + wb.z*xv.z + wb.w*xv.w;
        #pragma unroll
        for (int u = 0; u < 4; ++u) {
            float wau = (u==0)?wa.x:(u==1)?wa.y:(u==2)?wa.z:wa.w;
            float wbu = (u==0)?wb.x:(u==1)?wb.y:(u==2)?wb.z:wb.w;
            #pragma unroll
            for (int i4 = 0; i4 < 16; i4 += 4) {
                float4 kxv = *(const float4*)&KXt[k4+u][dh*16 + i4];
                macc[i4+0][0] += kxv.x*wau; macc[i4+0][1] += kxv.x*wbu;
                macc[i4+1][0] += kxv.y*wau; macc[i4+1][1] += kxv.y*wbu;
                macc[i4+2][0] += kxv.z*wau; macc[i4+2][1] += kxv.z*wbu;
                macc[i4+3][0] += kxv.w*wau; macc[i4+3][1] += kxv.w*wbu;
            }
        }
    }
    float bvc0 = bv_[c0], bvc1 = bv_[c0+1];
    if (dh == 0) {
        f[8192 + c0]     = v0 + (float)NN * bvc0;
        f[8192 + c0 + 1] = v1 + (float)NN * bvc1;
    }
    #pragma unroll
    for (int i = 0; i < 16; ++i) {
        int d = dh*16 + i;
        f[d*256 + c0]     = macc[i][0] + ks0[d]*bvc0;
        f[d*256 + c0 + 1] = macc[i][1] + ks0[d]*bvc1;
    }
}

// ---------------------------------------------------------------------------
// Kernel 3: outputs. Per block: batch b, 64 positions, BOTH streams.
// ---------------------------------------------------------------------------
__global__ __launch_bounds__(512, 2)
void k3_output(const float* __restrict__ qbuf, const float* __restrict__ fin,
               const float* __restrict__ g_gamma, const float* __restrict__ g_gammay,
               const float* __restrict__ g_gammacx, const float* __restrict__ g_gammacy,
               const float* __restrict__ g_wx1, const float* __restrict__ g_wx2,
               const float* __restrict__ g_wy1, const float* __restrict__ g_wy2,
               float* __restrict__ out)
{
    const int b = blockIdx.y;
    const int p0 = blockIdx.x * 64;
    const float* __restrict__ fx_ = fin + (size_t)(0*BB + b) * FIN_STRIDE;
    const float* __restrict__ fy_ = fin + (size_t)(1*BB + b) * FIN_STRIDE;

    __shared__ float Ms[64][260];
    __shared__ float At[64][132];
    __shared__ float vs[2][256];
    __shared__ float ksl[2][32];
    __shared__ float sv[128];

    const int tid = threadIdx.x;
    if (tid < 256) { vs[0][tid] = fx_[8192 + tid]; vs[1][tid] = fy_[8192 + tid]; }
    else if (tid < 320) { int t = tid - 256; ksl[t >> 5][t & 31] = ((t < 32) ? fx_ : fy_)[8448 + (t & 31)]; }
    __syncthreads();

    if (tid < 128) {
        const int str = tid >> 6;
        const int p = p0 + (tid & 63);
        const float* __restrict__ qp = qbuf + ((size_t)(str*BB + b) * NN + p) * DD;
        float q[32];
        float ss = 0.f;
        #pragma unroll
        for (int m = 0; m < 8; ++m) {
            float4 v = *(const float4*)(qp + m*4);
            q[m*4+0]=v.x; q[m*4+1]=v.y; q[m*4+2]=v.z; q[m*4+3]=v.w;
            ss += v.x*v.x + v.y*v.y + v.z*v.z + v.w*v.w;
        }
        float qn = rsqrtf(ss);
        float dK = 0.f, dKy = 0.f;
        #pragma unroll
        for (int d = 0; d < 32; ++d) { dK += q[d]*ksl[0][d]; dKy += q[d]*ksl[1][d]; }
        dK *= qn; dKy *= qn;
        float clo, chi, svr;
        if (str == 0) {
            float t1 = 1.f / ((float)NN + dK);
            float t2 = 1.f / ((float)NN + dKy);
            float a1 = g_gamma[0]   * g_wx1[0] * t1;
            float a2 = g_gammacx[0] * g_wx2[0] * t2;
            clo = a1 * qn; chi = a2 * qn; svr = a1 + a2;
        } else {
            float ty1 = 1.f / ((float)NN + dKy);
            float ty2 = 1.f / ((float)NN + dK);
            float b1 = g_gammay[0]  * g_wy1[0] * ty1;
            float b2 = g_gammacy[0] * g_wy2[0] * ty2;
            clo = b2 * qn; chi = b1 * qn; svr = b1 + b2;
        }
        sv[tid] = svr;
        #pragma unroll
        for (int k = 0; k < 32; ++k) At[k][tid]      = clo * q[k];
        #pragma unroll
        for (int k = 0; k < 32; ++k) At[32 + k][tid] = chi * q[k];
    } else {
        for (int f4i = tid - 128; f4i < 4096; f4i += 384) {
            int flat = f4i * 4;
            int k = flat >> 8, c = flat & 255;
            const float* __restrict__ srcp = (k < 32) ? (fx_ + k*256 + c) : (fy_ + (k-32)*256 + c);
            *(float4*)&Ms[k][c] = *(const float4*)srcp;
        }
    }
    __syncthreads();

    const int rg = tid >> 5, cg = tid & 31;
    const int r0 = rg * 8;
    const int cA = cg * 4, cB2 = 128 + cg * 4;
    float accr[8][8];
    #pragma unroll
    for (int i = 0; i < 8; ++i)
        #pragma unroll
        for (int m = 0; m < 8; ++m) accr[i][m] = 0.f;

    #pragma unroll 2
    for (int k = 0; k < 64; ++k) {
        float4 a0 = *(const float4*)&At[k][r0];
        float4 a1 = *(const float4*)&At[k][r0 + 4];
        float4 m0 = *(const float4*)&Ms[k][cA];
        float4 m1 = *(const float4*)&Ms[k][cB2];
        float av[8] = {a0.x, a0.y, a0.z, a0.w, a1.x, a1.y, a1.z, a1.w};
        #pragma unroll
        for (int i = 0; i < 8; ++i) {
            accr[i][0] += av[i]*m0.x; accr[i][1] += av[i]*m0.y;
            accr[i][2] += av[i]*m0.z; accr[i][3] += av[i]*m0.w;
            accr[i][4] += av[i]*m1.x; accr[i][5] += av[i]*m1.y;
            accr[i][6] += av[i]*m1.z; accr[i][7] += av[i]*m1.w;
        }
    }

    float* __restrict__ fxout = out;
    float* __restrict__ fyout = out + (size_t)BB * NN * CC;
    const int str = rg >> 3;
    const float* __restrict__ vrow = vs[str];
    float4 vA = *(const float4*)&vrow[cA];
    float4 vB = *(const float4*)&vrow[cB2];
    #pragma unroll
    for (int i = 0; i < 8; ++i) {
        int r = r0 + i;
        int p = p0 + (r & 63);
        float svr = sv[r];
        float4 o0 = make_float4(accr[i][0] + svr*vA.x, accr[i][1] + svr*vA.y,
                                accr[i][2] + svr*vA.z, accr[i][3] + svr*vA.w);
        float4 o1 = make_float4(accr[i][4] + svr*vB.x, accr[i][5] + svr*vB.y,
                                accr[i][6] + svr*vB.z, accr[i][7] + svr*vB.w);
        float* __restrict__ op = (str ? fyout : fxout) + ((size_t)b * NN + p) * CC;
        *(float4*)(op + cA)  = o0;
        *(float4*)(op + cB2) = o1;
    }
}

extern "C" void kernel_launch(void* const* d_in, const int* in_sizes, int n_in,
                              void* d_out, int out_size, void* d_ws, size_t ws_size,
                              hipStream_t stream)
{
    (void)in_sizes; (void)n_in; (void)out_size; (void)ws_size;
    const float* x   = (const float*)d_in[0];
    const float* y   = (const float*)d_in[1];
    const float* Wq  = (const float*)d_in[2];
    const float* bq  = (const float*)d_in[3];
    const float* Wk  = (const float*)d_in[4];
    const float* bk  = (const float*)d_in[5];
    const float* Wv  = (const float*)d_in[6];
    const float* bv  = (const float*)d_in[7];
    const float* Wqy = (const float*)d_in[8];
    const float* bqy = (const float*)d_in[9];
    const float* Wky = (const float*)d_in[10];
    const float* bky = (const float*)d_in[11];
    const float* Wvy = (const float*)d_in[12];
    const float* bvy = (const float*)d_in[13];

    float* ws   = (float*)d_ws;
    float* qbuf = ws;
    float* acc  = ws + ACC_OFF;
    float* fin  = ws + FIN_OFF;
    unsigned short* wbf = (unsigned short*)(ws + WBF_OFF);

    k0_cvt<<<128, 256, 0, stream>>>(Wk, Wq, Wky, Wqy, wbf);
    hipMemsetAsync(acc, 0, ACC_FLOATS * sizeof(float), stream);

    k1_proj<<<dim3(64, BB, 2), 256, 0, stream>>>(x, y, wbf, bk, bq, bky, bqy, qbuf, acc);
    k2_finalize<<<dim3(BB, 2), 256, 0, stream>>>(Wv, bv, Wvy, bvy, acc, fin);
    k3_output<<<dim3(NN/64, BB), 512, 0, stream>>>(qbuf, fin,
        (const float*)d_in[14], (const float*)d_in[15], (const float*)d_in[16], (const float*)d_in[17],
        (const float*)d_in[18], (const float*)d_in[19], (const float*)d_in[20], (const float*)d_in[21],
        (float*)d_out);
}

// Round 5
// 344.662 us; speedup vs baseline: 1.9678x; 1.9678x over previous
//
#include <hip/hip_runtime.h>

#define BB 8
#define NN 16384
#define CC 256
#define DD 32
#define EPSF 1e-6f

// ws layout (float units)
#define QBUF_FLOATS (2ull*BB*NN*DD)            // 32 MiB of normalized Q
#define ACC_STRIDE 8480                         // per (s,b): KX[32][256], xsum[256], ksum0[32]
#define ACC_OFF QBUF_FLOATS
#define ACC_FLOATS (16*ACC_STRIDE)
#define FIN_OFF (ACC_OFF + ACC_FLOATS)
#define FIN_STRIDE 8480
#define WBF_OFF (FIN_OFF + 16*FIN_STRIDE)       // 32768 ushort = 16384 floats

typedef __attribute__((ext_vector_type(8))) short bh8;
typedef __attribute__((ext_vector_type(4))) float f4;
typedef __attribute__((ext_vector_type(2))) unsigned int u32x2;

__device__ __forceinline__ unsigned int bfp(float f) {
    unsigned int u = __float_as_uint(f);
    return (u + 0x7FFFu + ((u >> 16) & 1u)) >> 16;   // RNE fp32->bf16 bits
}

#define MFMA16 __builtin_amdgcn_mfma_f32_16x16x32_bf16

// ---------------------------------------------------------------------------
// k0: convert the 4 projection weight matrices to bf16 once.
// ---------------------------------------------------------------------------
__global__ __launch_bounds__(256)
void k0_cvt(const float* __restrict__ Wk, const float* __restrict__ Wq,
            const float* __restrict__ Wky, const float* __restrict__ Wqy,
            unsigned short* __restrict__ wbf)
{
    int i = blockIdx.x * 256 + threadIdx.x;      // 0..32767
    const float* p = (i < 8192) ? Wk : (i < 16384) ? Wq : (i < 24576) ? Wky : Wqy;
    wbf[i] = (unsigned short)bfp(p[i & 8191]);
}

// ---------------------------------------------------------------------------
// k1: wave w owns d-tile w (w0,w1 = K rows 0-15/16-31; w2,w3 = Q).
//   GEMM1: D'[d][p] = W.X^T + bias; W A-frags loop-invariant in VGPRs.
//   X staged in [4p x 16c]-subtiled bf16 LDS (R4-verified layout).
//   Norms: in-reg over r + shfl over l4 + cross-wave via red[].
//   K -> Ksb [p][d]-subtiled bf16 (contiguous uint2 stores).
//   GEMM2: KX[d][c] += K^T.X; A (Ksb) and B (Xsub) frags via ds_read_b64_tr_b16
//   with counted lgkmcnt pipeline. KX partials -> pbuf (no atomics).
// ---------------------------------------------------------------------------
__global__ __launch_bounds__(256, 3)
void k1_proj(const float* __restrict__ x, const float* __restrict__ y,
             const unsigned short* __restrict__ wbf,
             const float* __restrict__ bk, const float* __restrict__ bq,
             const float* __restrict__ bky, const float* __restrict__ bqy,
             float* __restrict__ qbuf, float* __restrict__ acc,
             float* __restrict__ pbuf)
{
    const int b = blockIdx.y, s = blockIdx.z;
    const float* __restrict__ src = (s ? y : x) + (size_t)b * NN * CC;
    float* __restrict__ qb = qbuf + (size_t)(s*BB + b) * NN * DD;
    float* __restrict__ accsb = acc + (size_t)(s*BB + b) * ACC_STRIDE;
    float* __restrict__ pout = pbuf + ((size_t)((s*BB + b) * 64 + blockIdx.x)) * 8192;

    __shared__ unsigned short Xsub[16384];   // 32 KB subtiled bf16 X
    __shared__ unsigned short Ksb[2048];     // 4 KB [p][d]-subtiled bf16 K
    __shared__ float red[4][64];             // per-dtile norm partials
    __shared__ float xred[4][256];           // xsum cross-wave

    const int tid = threadIdx.x;
    const int w = tid >> 6, lane = tid & 63;
    const int l15 = lane & 15, l4 = lane >> 4;
    const int oct = lane & 31, lv = lane >> 5;

    // ---- loop-invariant weight A-frags (matrix: s*2 + (w>>1); rows 16*(w&1)+l15)
    const unsigned short* __restrict__ wm =
        wbf + (size_t)(s * 2 + (w >> 1)) * 8192 + (size_t)(16 * (w & 1) + l15) * 256 + 8 * l4;
    bh8 wf[8];
    #pragma unroll
    for (int ks = 0; ks < 8; ++ks) wf[ks] = *(const bh8*)(wm + 32 * ks);
    const float* __restrict__ bp = (w < 2) ? (s ? bky : bk) : (s ? bqy : bq);
    const f4 bias4 = *(const f4*)(bp + 16 * (w & 1) + 4 * l4);

    // ---- staging addresses (R4-verified subtile math)
    const int prow_lo = 2 * w + lv;                         // 0..7
    const int hv = (prow_lo >> 2) & 1;
    const int wbyte = (hv * 2048 + (oct >> 1) * 128 + (prow_lo & 3) * 32 + (oct & 1) * 16) ^ (hv << 4);
    // GEMM1 B-frag (X row-major): p = 16pt + l15, c = 32ks + 8l4
    int ab[4];
    #pragma unroll
    for (int pt = 0; pt < 4; ++pt) {
        int aq = 4 * pt + (l15 >> 2);
        ab[pt] = ((aq * 2048 + (l15 & 3) * 32 + (l4 & 1) * 16) ^ ((aq & 1) << 4)) + (l4 >> 1) * 128;
    }
    const unsigned xsub0 = (unsigned)(uintptr_t)&Xsub[0];
    const unsigned kbase = (unsigned)(uintptr_t)&Ksb[0];
    const unsigned btr0 = xsub0 + (unsigned)(2 * l4 * 2048 + 4 * w * 128 + l15 * 8);
    const unsigned atr0 = kbase + (unsigned)(2 * l4 * 256 + l15 * 8);

    f4 g2[2][4];
    #pragma unroll
    for (int dt = 0; dt < 2; ++dt)
        #pragma unroll
        for (int ct = 0; ct < 4; ++ct) g2[dt][ct] = (f4){0.f, 0.f, 0.f, 0.f};
    float xs[8];
    #pragma unroll
    for (int j = 0; j < 8; ++j) xs[j] = 0.f;
    float kreg[4] = {0.f, 0.f, 0.f, 0.f};

    for (int ch = 0; ch < 4; ++ch) {
        const int p0 = (blockIdx.x * 4 + ch) * 64;

        // ---- stage X chunk -> subtiled bf16 LDS
        #pragma unroll
        for (int it = 0; it < 8; ++it) {
            const float* gp = src + (size_t)(p0 + 8 * it + prow_lo) * CC + oct * 8;
            float4 va = *(const float4*)gp;
            float4 vb = *(const float4*)(gp + 4);
            xs[0] += va.x; xs[1] += va.y; xs[2] += va.z; xs[3] += va.w;
            xs[4] += vb.x; xs[5] += vb.y; xs[6] += vb.z; xs[7] += vb.w;
            uint4 pk;
            pk.x = bfp(va.x) | (bfp(va.y) << 16);
            pk.y = bfp(va.z) | (bfp(va.w) << 16);
            pk.z = bfp(vb.x) | (bfp(vb.y) << 16);
            pk.w = bfp(vb.z) | (bfp(vb.w) << 16);
            *(uint4*)((char*)Xsub + wbyte + it * 4096) = pk;
        }
        __syncthreads();

        // ---- GEMM1: D'[d][p] = W.X^T + bias  (A = wf regs, B = Xsub rows)
        f4 a1[4];
        #pragma unroll
        for (int pt = 0; pt < 4; ++pt) a1[pt] = bias4;
        #pragma unroll
        for (int ks = 0; ks < 8; ++ks) {
            #pragma unroll
            for (int pt = 0; pt < 4; ++pt) {
                bh8 xb = *(const bh8*)((const char*)Xsub + ab[pt] + ks * 256);
                a1[pt] = MFMA16(wf[ks], xb, a1[pt], 0, 0, 0);
            }
        }

        // ---- norm partials: sum over r in-reg, over l4 via shfl, cross-wave via red
        #pragma unroll
        for (int pt = 0; pt < 4; ++pt) {
            float ssv = a1[pt][0]*a1[pt][0] + a1[pt][1]*a1[pt][1]
                      + a1[pt][2]*a1[pt][2] + a1[pt][3]*a1[pt][3];
            ssv += __shfl_xor(ssv, 16);
            ssv += __shfl_xor(ssv, 32);
            if (l4 == 0) red[w][16 * pt + l15] = ssv;
        }
        __syncthreads();

        if (w < 2) {
            // K-waves: normalize, Ksb store, ksum accumulate
            #pragma unroll
            for (int pt = 0; pt < 4; ++pt) {
                int p = 16 * pt + l15;
                float n = rsqrtf(red[0][p] + red[1][p]);
                float k0 = a1[pt][0]*n, k1 = a1[pt][1]*n, k2 = a1[pt][2]*n, k3 = a1[pt][3]*n;
                kreg[0] += k0; kreg[1] += k1; kreg[2] += k2; kreg[3] += k3;
                unsigned lo = bfp(k0) | (bfp(k1) << 16);
                unsigned hi = bfp(k2) | (bfp(k3) << 16);
                *(uint2*)((char*)Ksb + (p >> 2) * 256 + (w & 1) * 128 + (p & 3) * 32 + 8 * l4)
                    = make_uint2(lo, hi);
            }
        } else {
            // Q-waves: normalize, float4 global store
            #pragma unroll
            for (int pt = 0; pt < 4; ++pt) {
                int p = 16 * pt + l15;
                float n = rsqrtf(red[2][p] + red[3][p]);
                f4 qv = { a1[pt][0]*n, a1[pt][1]*n, a1[pt][2]*n, a1[pt][3]*n };
                *(f4*)(qb + (size_t)(p0 + p) * DD + 16 * (w & 1) + 4 * l4) = qv;
            }
        }
        __syncthreads();

        // ---- GEMM2: KX[d][c] += K^T.X via tr-reads, counted lgkm pipeline
        #pragma unroll
        for (int ks2 = 0; ks2 < 2; ++ks2) {
            u32x2 ta0, ta1, ta2, ta3;
            u32x2 tb0, tb1, tb2, tb3, tb4, tb5, tb6, tb7;
            const unsigned ka = atr0 + (unsigned)(ks2 * 2048);
            asm volatile("ds_read_b64_tr_b16 %0, %1" : "=v"(ta0) : "v"(ka));
            asm volatile("ds_read_b64_tr_b16 %0, %1" : "=v"(ta1) : "v"(ka + 256u));
            asm volatile("ds_read_b64_tr_b16 %0, %1" : "=v"(ta2) : "v"(ka + 128u));
            asm volatile("ds_read_b64_tr_b16 %0, %1" : "=v"(ta3) : "v"(ka + 384u));
            const unsigned kb = btr0 + (unsigned)(ks2 * 16384);
            asm volatile("ds_read_b64_tr_b16 %0, %1" : "=v"(tb0) : "v"(kb));
            asm volatile("ds_read_b64_tr_b16 %0, %1" : "=v"(tb1) : "v"((kb + 2048u) ^ 16u));
            asm volatile("ds_read_b64_tr_b16 %0, %1" : "=v"(tb2) : "v"(kb + 128u));
            asm volatile("ds_read_b64_tr_b16 %0, %1" : "=v"(tb3) : "v"((kb + 2176u) ^ 16u));
            asm volatile("ds_read_b64_tr_b16 %0, %1" : "=v"(tb4) : "v"(kb + 256u));
            asm volatile("ds_read_b64_tr_b16 %0, %1" : "=v"(tb5) : "v"((kb + 2304u) ^ 16u));
            asm volatile("ds_read_b64_tr_b16 %0, %1" : "=v"(tb6) : "v"(kb + 384u));
            asm volatile("ds_read_b64_tr_b16 %0, %1" : "=v"(tb7) : "v"((kb + 2432u) ^ 16u));
            asm volatile("s_waitcnt lgkmcnt(8)" ::: "memory");
            __builtin_amdgcn_sched_barrier(0);
            union { unsigned u[4]; bh8 v; } A0, A1;
            A0.u[0] = ta0[0]; A0.u[1] = ta0[1]; A0.u[2] = ta1[0]; A0.u[3] = ta1[1];
            A1.u[0] = ta2[0]; A1.u[1] = ta2[1]; A1.u[2] = ta3[0]; A1.u[3] = ta3[1];
            asm volatile("s_waitcnt lgkmcnt(6)" ::: "memory");
            __builtin_amdgcn_sched_barrier(0);
            {
                union { unsigned u[4]; bh8 v; } Bc;
                Bc.u[0] = tb0[0]; Bc.u[1] = tb0[1]; Bc.u[2] = tb1[0]; Bc.u[3] = tb1[1];
                g2[0][0] = MFMA16(A0.v, Bc.v, g2[0][0], 0, 0, 0);
                g2[1][0] = MFMA16(A1.v, Bc.v, g2[1][0], 0, 0, 0);
            }
            asm volatile("s_waitcnt lgkmcnt(4)" ::: "memory");
            __builtin_amdgcn_sched_barrier(0);
            {
                union { unsigned u[4]; bh8 v; } Bc;
                Bc.u[0] = tb2[0]; Bc.u[1] = tb2[1]; Bc.u[2] = tb3[0]; Bc.u[3] = tb3[1];
                g2[0][1] = MFMA16(A0.v, Bc.v, g2[0][1], 0, 0, 0);
                g2[1][1] = MFMA16(A1.v, Bc.v, g2[1][1], 0, 0, 0);
            }
            asm volatile("s_waitcnt lgkmcnt(2)" ::: "memory");
            __builtin_amdgcn_sched_barrier(0);
            {
                union { unsigned u[4]; bh8 v; } Bc;
                Bc.u[0] = tb4[0]; Bc.u[1] = tb4[1]; Bc.u[2] = tb5[0]; Bc.u[3] = tb5[1];
                g2[0][2] = MFMA16(A0.v, Bc.v, g2[0][2], 0, 0, 0);
                g2[1][2] = MFMA16(A1.v, Bc.v, g2[1][2], 0, 0, 0);
            }
            asm volatile("s_waitcnt lgkmcnt(0)" ::: "memory");
            __builtin_amdgcn_sched_barrier(0);
            {
                union { unsigned u[4]; bh8 v; } Bc;
                Bc.u[0] = tb6[0]; Bc.u[1] = tb6[1]; Bc.u[2] = tb7[0]; Bc.u[3] = tb7[1];
                g2[0][3] = MFMA16(A0.v, Bc.v, g2[0][3], 0, 0, 0);
                g2[1][3] = MFMA16(A1.v, Bc.v, g2[1][3], 0, 0, 0);
            }
        }
        __syncthreads();
    }

    // ---- epilogue: KX partials -> pbuf (plain stores)
    #pragma unroll
    for (int dt = 0; dt < 2; ++dt)
        #pragma unroll
        for (int ct = 0; ct < 4; ++ct)
            #pragma unroll
            for (int r = 0; r < 4; ++r)
                pout[(16 * dt + 4 * l4 + r) * 256 + 64 * w + 16 * ct + l15] = g2[dt][ct][r];

    // ---- xsum: lv-pair reduce -> xred -> one atomic per c
    #pragma unroll
    for (int j = 0; j < 8; ++j) xs[j] += __shfl_xor(xs[j], 32);
    if (lv == 0) {
        #pragma unroll
        for (int j = 0; j < 8; ++j) xred[w][oct * 8 + j] = xs[j];
    }
    __syncthreads();
    {
        float v = xred[0][tid] + xred[1][tid] + xred[2][tid] + xred[3][tid];
        atomicAdd(accsb + 8192 + tid, v);
    }
    // ---- ksum
    if (w < 2) {
        #pragma unroll
        for (int r = 0; r < 4; ++r) {
            float v = kreg[r];
            v += __shfl_xor(v, 1); v += __shfl_xor(v, 2);
            v += __shfl_xor(v, 4); v += __shfl_xor(v, 8);
            if (l15 == 0) atomicAdd(accsb + 8448 + 16 * (w & 1) + 4 * l4 + r, v);
        }
    }
}

// ---------------------------------------------------------------------------
// k2a: reduce 64 per-block KX partials -> acc (grid: BB x 2 x 8 c-slices)
// ---------------------------------------------------------------------------
__global__ __launch_bounds__(256)
void k2a_reduce(const float* __restrict__ pbuf, float* __restrict__ acc)
{
    const int b = blockIdx.x, s = blockIdx.y, cs = blockIdx.z;
    const float* __restrict__ p = pbuf + (size_t)(s*BB + b) * 64 * 8192;
    float* __restrict__ a = acc + (size_t)(s*BB + b) * ACC_STRIDE;
    const int d = threadIdx.x >> 3, c = cs * 32 + (threadIdx.x & 7) * 4;
    f4 v = (f4){0.f, 0.f, 0.f, 0.f};
    for (int j = 0; j < 64; ++j)
        v += *(const f4*)(p + (size_t)j * 8192 + d * 256 + c);
    *(f4*)(a + d * 256 + c) = v;
}

// ---------------------------------------------------------------------------
// Kernel 2: finalize per (b,s): mat = KX @ Wv^T + ksum0 (x) bv ; vsum = Wv@xsum + N*bv
// ---------------------------------------------------------------------------
__global__ __launch_bounds__(256, 2)
void k2_finalize(const float* __restrict__ Wv, const float* __restrict__ bv,
                 const float* __restrict__ Wvy, const float* __restrict__ bvy,
                 const float* __restrict__ acc, float* __restrict__ fin)
{
    const int b = blockIdx.x, s = blockIdx.y;
    const float* __restrict__ Wv_ = s ? Wvy : Wv;
    const float* __restrict__ bv_ = s ? bvy : bv;
    const float* __restrict__ a = acc + (size_t)(s*BB + b) * ACC_STRIDE;
    float* __restrict__ f = fin + (size_t)(s*BB + b) * FIN_STRIDE;

    __shared__ float KXt[256][36];
    __shared__ float xsh[256];
    __shared__ float ks0[32];

    const int tid = threadIdx.x;
    for (int d = 0; d < 32; ++d) KXt[tid][d] = a[d*256 + tid];
    xsh[tid] = a[8192 + tid];
    if (tid < 32) { float v = a[8448 + tid]; ks0[tid] = v; f[8448 + tid] = v + EPSF; }
    __syncthreads();

    const int dh = tid >> 7;
    const int c0 = (tid & 127) * 2;
    float macc[16][2];
    #pragma unroll
    for (int i = 0; i < 16; ++i) { macc[i][0]=0.f; macc[i][1]=0.f; }
    float v0 = 0.f, v1 = 0.f;

    for (int k4 = 0; k4 < 256; k4 += 4) {
        float4 wa = *(const float4*)(Wv_ + (size_t)c0*256 + k4);
        float4 wb = *(const float4*)(Wv_ + (size_t)(c0+1)*256 + k4);
        float4 xv = *(const float4*)&xsh[k4];
        v0 += wa.x*xv.x + wa.y*xv.y + wa.z*xv.z + wa.w*xv.w;
        v1 += wb.x*xv.x + wb.y*xv.y + wb.z*xv.z + wb.w*xv.w;
        #pragma unroll
        for (int u = 0; u < 4; ++u) {
            float wau = (u==0)?wa.x:(u==1)?wa.y:(u==2)?wa.z:wa.w;
            float wbu = (u==0)?wb.x:(u==1)?wb.y:(u==2)?wb.z:wb.w;
            #pragma unroll
            for (int i4 = 0; i4 < 16; i4 += 4) {
                float4 kxv = *(const float4*)&KXt[k4+u][dh*16 + i4];
                macc[i4+0][0] += kxv.x*wau; macc[i4+0][1] += kxv.x*wbu;
                macc[i4+1][0] += kxv.y*wau; macc[i4+1][1] += kxv.y*wbu;
                macc[i4+2][0] += kxv.z*wau; macc[i4+2][1] += kxv.z*wbu;
                macc[i4+3][0] += kxv.w*wau; macc[i4+3][1] += kxv.w*wbu;
            }
        }
    }
    float bvc0 = bv_[c0], bvc1 = bv_[c0+1];
    if (dh == 0) {
        f[8192 + c0]     = v0 + (float)NN * bvc0;
        f[8192 + c0 + 1] = v1 + (float)NN * bvc1;
    }
    #pragma unroll
    for (int i = 0; i < 16; ++i) {
        int d = dh*16 + i;
        f[d*256 + c0]     = macc[i][0] + ks0[d]*bvc0;
        f[d*256 + c0 + 1] = macc[i][1] + ks0[d]*bvc1;
    }
}

// ---------------------------------------------------------------------------
// Kernel 3: outputs. Per block: batch b, 64 positions, BOTH streams.
// ---------------------------------------------------------------------------
__global__ __launch_bounds__(512, 2)
void k3_output(const float* __restrict__ qbuf, const float* __restrict__ fin,
               const float* __restrict__ g_gamma, const float* __restrict__ g_gammay,
               const float* __restrict__ g_gammacx, const float* __restrict__ g_gammacy,
               const float* __restrict__ g_wx1, const float* __restrict__ g_wx2,
               const float* __restrict__ g_wy1, const float* __restrict__ g_wy2,
               float* __restrict__ out)
{
    const int b = blockIdx.y;
    const int p0 = blockIdx.x * 64;
    const float* __restrict__ fx_ = fin + (size_t)(0*BB + b) * FIN_STRIDE;
    const float* __restrict__ fy_ = fin + (size_t)(1*BB + b) * FIN_STRIDE;

    __shared__ float Ms[64][260];
    __shared__ float At[64][132];
    __shared__ float vs[2][256];
    __shared__ float ksl[2][32];
    __shared__ float sv[128];

    const int tid = threadIdx.x;
    if (tid < 256) { vs[0][tid] = fx_[8192 + tid]; vs[1][tid] = fy_[8192 + tid]; }
    else if (tid < 320) { int t = tid - 256; ksl[t >> 5][t & 31] = ((t < 32) ? fx_ : fy_)[8448 + (t & 31)]; }
    __syncthreads();

    if (tid < 128) {
        const int str = tid >> 6;
        const int p = p0 + (tid & 63);
        const float* __restrict__ qp = qbuf + ((size_t)(str*BB + b) * NN + p) * DD;
        float q[32];
        float ss = 0.f;
        #pragma unroll
        for (int m = 0; m < 8; ++m) {
            float4 v = *(const float4*)(qp + m*4);
            q[m*4+0]=v.x; q[m*4+1]=v.y; q[m*4+2]=v.z; q[m*4+3]=v.w;
            ss += v.x*v.x + v.y*v.y + v.z*v.z + v.w*v.w;
        }
        float qn = rsqrtf(ss);
        float dK = 0.f, dKy = 0.f;
        #pragma unroll
        for (int d = 0; d < 32; ++d) { dK += q[d]*ksl[0][d]; dKy += q[d]*ksl[1][d]; }
        dK *= qn; dKy *= qn;
        float clo, chi, svr;
        if (str == 0) {
            float t1 = 1.f / ((float)NN + dK);
            float t2 = 1.f / ((float)NN + dKy);
            float a1 = g_gamma[0]   * g_wx1[0] * t1;
            float a2 = g_gammacx[0] * g_wx2[0] * t2;
            clo = a1 * qn; chi = a2 * qn; svr = a1 + a2;
        } else {
            float ty1 = 1.f / ((float)NN + dKy);
            float ty2 = 1.f / ((float)NN + dK);
            float b1 = g_gammay[0]  * g_wy1[0] * ty1;
            float b2 = g_gammacy[0] * g_wy2[0] * ty2;
            clo = b2 * qn; chi = b1 * qn; svr = b1 + b2;
        }
        sv[tid] = svr;
        #pragma unroll
        for (int k = 0; k < 32; ++k) At[k][tid]      = clo * q[k];
        #pragma unroll
        for (int k = 0; k < 32; ++k) At[32 + k][tid] = chi * q[k];
    } else {
        for (int f4i = tid - 128; f4i < 4096; f4i += 384) {
            int flat = f4i * 4;
            int k = flat >> 8, c = flat & 255;
            const float* __restrict__ srcp = (k < 32) ? (fx_ + k*256 + c) : (fy_ + (k-32)*256 + c);
            *(float4*)&Ms[k][c] = *(const float4*)srcp;
        }
    }
    __syncthreads();

    const int rg = tid >> 5, cg = tid & 31;
    const int r0 = rg * 8;
    const int cA = cg * 4, cB2 = 128 + cg * 4;
    float accr[8][8];
    #pragma unroll
    for (int i = 0; i < 8; ++i)
        #pragma unroll
        for (int m = 0; m < 8; ++m) accr[i][m] = 0.f;

    #pragma unroll 2
    for (int k = 0; k < 64; ++k) {
        float4 a0 = *(const float4*)&At[k][r0];
        float4 a1 = *(const float4*)&At[k][r0 + 4];
        float4 m0 = *(const float4*)&Ms[k][cA];
        float4 m1 = *(const float4*)&Ms[k][cB2];
        float av[8] = {a0.x, a0.y, a0.z, a0.w, a1.x, a1.y, a1.z, a1.w};
        #pragma unroll
        for (int i = 0; i < 8; ++i) {
            accr[i][0] += av[i]*m0.x; accr[i][1] += av[i]*m0.y;
            accr[i][2] += av[i]*m0.z; accr[i][3] += av[i]*m0.w;
            accr[i][4] += av[i]*m1.x; accr[i][5] += av[i]*m1.y;
            accr[i][6] += av[i]*m1.z; accr[i][7] += av[i]*m1.w;
        }
    }

    float* __restrict__ fxout = out;
    float* __restrict__ fyout = out + (size_t)BB * NN * CC;
    const int str = rg >> 3;
    const float* __restrict__ vrow = vs[str];
    float4 vA = *(const float4*)&vrow[cA];
    float4 vB = *(const float4*)&vrow[cB2];
    #pragma unroll
    for (int i = 0; i < 8; ++i) {
        int r = r0 + i;
        int p = p0 + (r & 63);
        float svr = sv[r];
        float4 o0 = make_float4(accr[i][0] + svr*vA.x, accr[i][1] + svr*vA.y,
                                accr[i][2] + svr*vA.z, accr[i][3] + svr*vA.w);
        float4 o1 = make_float4(accr[i][4] + svr*vB.x, accr[i][5] + svr*vB.y,
                                accr[i][6] + svr*vB.z, accr[i][7] + svr*vB.w);
        float* __restrict__ op = (str ? fyout : fxout) + ((size_t)b * NN + p) * CC;
        *(float4*)(op + cA)  = o0;
        *(float4*)(op + cB2) = o1;
    }
}

extern "C" void kernel_launch(void* const* d_in, const int* in_sizes, int n_in,
                              void* d_out, int out_size, void* d_ws, size_t ws_size,
                              hipStream_t stream)
{
    (void)in_sizes; (void)n_in; (void)out_size; (void)ws_size;
    const float* x   = (const float*)d_in[0];
    const float* y   = (const float*)d_in[1];
    const float* Wq  = (const float*)d_in[2];
    const float* bq  = (const float*)d_in[3];
    const float* Wk  = (const float*)d_in[4];
    const float* bk  = (const float*)d_in[5];
    const float* Wv  = (const float*)d_in[6];
    const float* bv  = (const float*)d_in[7];
    const float* Wqy = (const float*)d_in[8];
    const float* bqy = (const float*)d_in[9];
    const float* Wky = (const float*)d_in[10];
    const float* bky = (const float*)d_in[11];
    const float* Wvy = (const float*)d_in[12];
    const float* bvy = (const float*)d_in[13];

    float* ws   = (float*)d_ws;
    float* qbuf = ws;
    float* acc  = ws + ACC_OFF;
    float* fin  = ws + FIN_OFF;
    unsigned short* wbf = (unsigned short*)(ws + WBF_OFF);
    float* pbuf = (float*)d_out;    // scratch: fully consumed by k2a before k3 overwrites

    k0_cvt<<<128, 256, 0, stream>>>(Wk, Wq, Wky, Wqy, wbf);
    hipMemsetAsync(acc, 0, ACC_FLOATS * sizeof(float), stream);

    k1_proj<<<dim3(64, BB, 2), 256, 0, stream>>>(x, y, wbf, bk, bq, bky, bqy, qbuf, acc, pbuf);
    k2a_reduce<<<dim3(BB, 2, 8), 256, 0, stream>>>(pbuf, acc);
    k2_finalize<<<dim3(BB, 2), 256, 0, stream>>>(Wv, bv, Wvy, bvy, acc, fin);
    k3_output<<<dim3(NN/64, BB), 512, 0, stream>>>(qbuf, fin,
        (const float*)d_in[14], (const float*)d_in[15], (const float*)d_in[16], (const float*)d_in[17],
        (const float*)d_in[18], (const float*)d_in[19], (const float*)d_in[20], (const float*)d_in[21],
        (float*)d_out);
}

// Round 6
// 245.280 us; speedup vs baseline: 2.7651x; 1.4052x over previous
//
#include <hip/hip_runtime.h>

#define BB 8
#define NN 16384
#define CC 256
#define DD 32
#define EPSF 1e-6f

// ws layout (float units)
#define QBUF_FLOATS (2ull*BB*NN*DD)            // reserved (qbuf now bf16, uses half)
#define ACC_STRIDE 8480                         // per (s,b): KX[32][256], xsum[256], ksum0[32]
#define ACC_OFF QBUF_FLOATS
#define ACC_FLOATS (16*ACC_STRIDE)
#define FIN_OFF (ACC_OFF + ACC_FLOATS)
#define FIN_STRIDE 8480
#define WBF_OFF (FIN_OFF + 16*FIN_STRIDE)       // 32768 ushort

typedef __attribute__((ext_vector_type(8))) short bh8;
typedef __attribute__((ext_vector_type(4))) float f4;
typedef __attribute__((ext_vector_type(2))) unsigned int u32x2;

__device__ __forceinline__ unsigned int bfp(float f) {
    unsigned int u = __float_as_uint(f);
    return (u + 0x7FFFu + ((u >> 16) & 1u)) >> 16;   // RNE fp32->bf16 bits
}
__device__ __forceinline__ float bf2f(unsigned int h) {
    return __uint_as_float(h << 16);
}

#define MFMA16 __builtin_amdgcn_mfma_f32_16x16x32_bf16

// lgkm-only barrier: LDS visibility without draining vmcnt (keeps global loads in flight)
#define LBAR() do { \
    asm volatile("s_waitcnt lgkmcnt(0)" ::: "memory"); \
    __builtin_amdgcn_s_barrier(); \
    __builtin_amdgcn_sched_barrier(0); \
} while (0)

// ---------------------------------------------------------------------------
// k0: convert the 4 projection weight matrices to bf16 once.
// ---------------------------------------------------------------------------
__global__ __launch_bounds__(256)
void k0_cvt(const float* __restrict__ Wk, const float* __restrict__ Wq,
            const float* __restrict__ Wky, const float* __restrict__ Wqy,
            unsigned short* __restrict__ wbf)
{
    int i = blockIdx.x * 256 + threadIdx.x;
    const float* p = (i < 8192) ? Wk : (i < 16384) ? Wq : (i < 24576) ? Wky : Wqy;
    wbf[i] = (unsigned short)bfp(p[i & 8191]);
}

// ---------------------------------------------------------------------------
// k1: 32-row chunks x8, double-buffered LDS, reg-staged global loads crossing
//     lgkm-only barriers. Wave w = d-tile (w0/w1 = K halves, w2/w3 = Q halves).
//     GEMM1: D'[d][p] = W.X^T + bias (W frags in VGPRs).
//     GEMM2: KX[d][c] += K^T.X via ds_read_b64_tr_b16, counted lgkm pipeline.
// ---------------------------------------------------------------------------
__global__ __launch_bounds__(256, 3)
void k1_proj(const float* __restrict__ x, const float* __restrict__ y,
             const unsigned short* __restrict__ wbf,
             const float* __restrict__ bk, const float* __restrict__ bq,
             const float* __restrict__ bky, const float* __restrict__ bqy,
             unsigned short* __restrict__ qbuf16, float* __restrict__ acc,
             float* __restrict__ pbuf)
{
    const int b = blockIdx.y, s = blockIdx.z;
    const float* __restrict__ src = (s ? y : x) + (size_t)b * NN * CC;
    unsigned short* __restrict__ qb = qbuf16 + (size_t)(s*BB + b) * NN * DD;
    float* __restrict__ accsb = acc + (size_t)(s*BB + b) * ACC_STRIDE;
    float* __restrict__ pout = pbuf + ((size_t)((s*BB + b) * 64 + blockIdx.x)) * 8192;

    __shared__ unsigned short Xsub[2][8192];   // 2 x 16 KB subtiled bf16 (32 rows each)
    __shared__ unsigned short Ksb[1024];       // 2 KB [p][d]-subtiled bf16 K (32 p)
    __shared__ float red[4][32];               // norm partials
    __shared__ float xred[4][256];             // xsum cross-wave

    const int tid = threadIdx.x;
    const int w = tid >> 6, lane = tid & 63;
    const int l15 = lane & 15, l4 = lane >> 4;
    const int oct = lane & 31;
    const int rower = tid >> 5;                // 0..7

    // weight frags: matrix (s*2 + (w>>1)), rows 16*(w&1)+l15
    const unsigned short* __restrict__ wm =
        wbf + (size_t)(s * 2 + (w >> 1)) * 8192 + (size_t)(16 * (w & 1) + l15) * 256 + 8 * l4;
    bh8 wf[8];
    #pragma unroll
    for (int ks = 0; ks < 8; ++ks) wf[ks] = *(const bh8*)(wm + 32 * ks);
    const float* __restrict__ bp = (w < 2) ? (s ? bky : bk) : (s ? bqy : bq);
    const f4 bias4 = *(const f4*)(bp + 16 * (w & 1) + 4 * l4);

    // staging LDS byte (row r = it*8 + rower, cols oct*8..+7), it stride 4096
    const int hv = (rower >> 2) & 1;
    const int wbyte0 = (hv * 2048 + (oct >> 1) * 128 + (rower & 3) * 32 + (oct & 1) * 16) ^ (hv << 4);
    // GEMM1 B-frag: p = 16*pt + l15, c = 32ks+8l4
    int ab[2];
    #pragma unroll
    for (int pt = 0; pt < 2; ++pt) {
        int aq = 4 * pt + (l15 >> 2);
        ab[pt] = ((aq * 2048 + (l15 & 3) * 32 + (l4 & 1) * 16) ^ ((aq & 1) << 4)) + (l4 >> 1) * 128;
    }
    const unsigned xb0 = (unsigned)(uintptr_t)&Xsub[0][0];
    const unsigned kbase = (unsigned)(uintptr_t)&Ksb[0];
    const unsigned btr_rel = (unsigned)(2 * l4 * 2048 + 4 * w * 128 + l15 * 8);
    const unsigned atr = kbase + (unsigned)(2 * l4 * 256 + l15 * 8);

    f4 g2[2][4];
    #pragma unroll
    for (int dt = 0; dt < 2; ++dt)
        #pragma unroll
        for (int ct = 0; ct < 4; ++ct) g2[dt][ct] = (f4){0.f, 0.f, 0.f, 0.f};
    float xs[8];
    #pragma unroll
    for (int j = 0; j < 8; ++j) xs[j] = 0.f;
    float kreg[4] = {0.f, 0.f, 0.f, 0.f};

    const float* __restrict__ gbase = src + (size_t)(blockIdx.x * 256 + rower) * CC + oct * 8;
    float4 va[4], vb[4];

    // prologue: issue chunk 0 loads
    #pragma unroll
    for (int it = 0; it < 4; ++it) {
        const float* g = gbase + (size_t)(it * 8) * CC;
        va[it] = *(const float4*)g;
        vb[it] = *(const float4*)(g + 4);
    }

    for (int ch = 0; ch < 8; ++ch) {
        const int cur = ch & 1;
        char* xcur = (char*)&Xsub[cur][0];

        // ---- consume regs -> pack -> LDS; then issue next chunk's loads
        #pragma unroll
        for (int it = 0; it < 4; ++it) {
            float4 A = va[it], B = vb[it];
            xs[0] += A.x; xs[1] += A.y; xs[2] += A.z; xs[3] += A.w;
            xs[4] += B.x; xs[5] += B.y; xs[6] += B.z; xs[7] += B.w;
            uint4 pk;
            pk.x = bfp(A.x) | (bfp(A.y) << 16);
            pk.y = bfp(A.z) | (bfp(A.w) << 16);
            pk.z = bfp(B.x) | (bfp(B.y) << 16);
            pk.w = bfp(B.z) | (bfp(B.w) << 16);
            *(uint4*)(xcur + wbyte0 + it * 4096) = pk;
        }
        if (ch < 7) {
            const float* gn = gbase + (size_t)((ch + 1) * 32) * CC;
            #pragma unroll
            for (int it = 0; it < 4; ++it) {
                const float* g = gn + (size_t)(it * 8) * CC;
                va[it] = *(const float4*)g;
                vb[it] = *(const float4*)(g + 4);
            }
        }
        LBAR();   // S1: Xsub[cur] visible; global loads stay in flight

        // ---- GEMM1: D'[d][p] = W.X^T + bias
        f4 a1[2];
        #pragma unroll
        for (int pt = 0; pt < 2; ++pt) a1[pt] = bias4;
        #pragma unroll
        for (int ks = 0; ks < 8; ++ks) {
            #pragma unroll
            for (int pt = 0; pt < 2; ++pt) {
                bh8 xbv = *(const bh8*)(xcur + ab[pt] + ks * 256);
                a1[pt] = MFMA16(wf[ks], xbv, a1[pt], 0, 0, 0);
            }
        }

        // ---- norm partials
        #pragma unroll
        for (int pt = 0; pt < 2; ++pt) {
            float ssv = a1[pt][0]*a1[pt][0] + a1[pt][1]*a1[pt][1]
                      + a1[pt][2]*a1[pt][2] + a1[pt][3]*a1[pt][3];
            ssv += __shfl_xor(ssv, 16);
            ssv += __shfl_xor(ssv, 32);
            if (l4 == 0) red[w][16 * pt + l15] = ssv;
        }
        LBAR();   // S2: red visible

        if (w < 2) {
            #pragma unroll
            for (int pt = 0; pt < 2; ++pt) {
                int p = 16 * pt + l15;
                float n = rsqrtf(red[0][p] + red[1][p]);
                float k0 = a1[pt][0]*n, k1 = a1[pt][1]*n, k2 = a1[pt][2]*n, k3 = a1[pt][3]*n;
                kreg[0] += k0; kreg[1] += k1; kreg[2] += k2; kreg[3] += k3;
                unsigned lo = bfp(k0) | (bfp(k1) << 16);
                unsigned hi = bfp(k2) | (bfp(k3) << 16);
                *(uint2*)((char*)Ksb + (p >> 2) * 256 + (w & 1) * 128 + (p & 3) * 32 + 8 * l4)
                    = make_uint2(lo, hi);
            }
        } else {
            #pragma unroll
            for (int pt = 0; pt < 2; ++pt) {
                int p = 16 * pt + l15;
                float n = rsqrtf(red[2][p] + red[3][p]);
                unsigned lo = bfp(a1[pt][0]*n) | (bfp(a1[pt][1]*n) << 16);
                unsigned hi = bfp(a1[pt][2]*n) | (bfp(a1[pt][3]*n) << 16);
                *(uint2*)(qb + (size_t)(blockIdx.x*256 + ch*32 + p) * DD + 16 * (w & 1) + 4 * l4)
                    = make_uint2(lo, hi);
            }
        }
        LBAR();   // S3: Ksb visible

        // ---- GEMM2: KX += K^T.X via tr-reads, counted lgkm pipeline
        {
            const unsigned kb = xb0 + (unsigned)(cur * 16384) + btr_rel;
            u32x2 ta0, ta1, ta2, ta3, tb0, tb1, tb2, tb3, tb4, tb5, tb6, tb7;
            asm volatile("ds_read_b64_tr_b16 %0, %1" : "=v"(ta0) : "v"(atr));
            asm volatile("ds_read_b64_tr_b16 %0, %1" : "=v"(ta1) : "v"(atr + 256u));
            asm volatile("ds_read_b64_tr_b16 %0, %1" : "=v"(ta2) : "v"(atr + 128u));
            asm volatile("ds_read_b64_tr_b16 %0, %1" : "=v"(ta3) : "v"(atr + 384u));
            asm volatile("ds_read_b64_tr_b16 %0, %1" : "=v"(tb0) : "v"(kb));
            asm volatile("ds_read_b64_tr_b16 %0, %1" : "=v"(tb1) : "v"((kb + 2048u) ^ 16u));
            asm volatile("ds_read_b64_tr_b16 %0, %1" : "=v"(tb2) : "v"(kb + 128u));
            asm volatile("ds_read_b64_tr_b16 %0, %1" : "=v"(tb3) : "v"((kb + 2176u) ^ 16u));
            asm volatile("ds_read_b64_tr_b16 %0, %1" : "=v"(tb4) : "v"(kb + 256u));
            asm volatile("ds_read_b64_tr_b16 %0, %1" : "=v"(tb5) : "v"((kb + 2304u) ^ 16u));
            asm volatile("ds_read_b64_tr_b16 %0, %1" : "=v"(tb6) : "v"(kb + 384u));
            asm volatile("ds_read_b64_tr_b16 %0, %1" : "=v"(tb7) : "v"((kb + 2432u) ^ 16u));
            asm volatile("s_waitcnt lgkmcnt(8)" ::: "memory");
            __builtin_amdgcn_sched_barrier(0);
            union { unsigned u[4]; bh8 v; } A0, A1;
            A0.u[0] = ta0[0]; A0.u[1] = ta0[1]; A0.u[2] = ta1[0]; A0.u[3] = ta1[1];
            A1.u[0] = ta2[0]; A1.u[1] = ta2[1]; A1.u[2] = ta3[0]; A1.u[3] = ta3[1];
            asm volatile("s_waitcnt lgkmcnt(6)" ::: "memory");
            __builtin_amdgcn_sched_barrier(0);
            {
                union { unsigned u[4]; bh8 v; } Bc;
                Bc.u[0] = tb0[0]; Bc.u[1] = tb0[1]; Bc.u[2] = tb1[0]; Bc.u[3] = tb1[1];
                g2[0][0] = MFMA16(A0.v, Bc.v, g2[0][0], 0, 0, 0);
                g2[1][0] = MFMA16(A1.v, Bc.v, g2[1][0], 0, 0, 0);
            }
            asm volatile("s_waitcnt lgkmcnt(4)" ::: "memory");
            __builtin_amdgcn_sched_barrier(0);
            {
                union { unsigned u[4]; bh8 v; } Bc;
                Bc.u[0] = tb2[0]; Bc.u[1] = tb2[1]; Bc.u[2] = tb3[0]; Bc.u[3] = tb3[1];
                g2[0][1] = MFMA16(A0.v, Bc.v, g2[0][1], 0, 0, 0);
                g2[1][1] = MFMA16(A1.v, Bc.v, g2[1][1], 0, 0, 0);
            }
            asm volatile("s_waitcnt lgkmcnt(2)" ::: "memory");
            __builtin_amdgcn_sched_barrier(0);
            {
                union { unsigned u[4]; bh8 v; } Bc;
                Bc.u[0] = tb4[0]; Bc.u[1] = tb4[1]; Bc.u[2] = tb5[0]; Bc.u[3] = tb5[1];
                g2[0][2] = MFMA16(A0.v, Bc.v, g2[0][2], 0, 0, 0);
                g2[1][2] = MFMA16(A1.v, Bc.v, g2[1][2], 0, 0, 0);
            }
            asm volatile("s_waitcnt lgkmcnt(0)" ::: "memory");
            __builtin_amdgcn_sched_barrier(0);
            {
                union { unsigned u[4]; bh8 v; } Bc;
                Bc.u[0] = tb6[0]; Bc.u[1] = tb6[1]; Bc.u[2] = tb7[0]; Bc.u[3] = tb7[1];
                g2[0][3] = MFMA16(A0.v, Bc.v, g2[0][3], 0, 0, 0);
                g2[1][3] = MFMA16(A1.v, Bc.v, g2[1][3], 0, 0, 0);
            }
        }
    }

    // ---- epilogue
    #pragma unroll
    for (int dt = 0; dt < 2; ++dt)
        #pragma unroll
        for (int ct = 0; ct < 4; ++ct)
            #pragma unroll
            for (int r = 0; r < 4; ++r)
                pout[(16 * dt + 4 * l4 + r) * 256 + 64 * w + 16 * ct + l15] = g2[dt][ct][r];

    #pragma unroll
    for (int j = 0; j < 8; ++j) xs[j] += __shfl_xor(xs[j], 32);
    if ((lane >> 5) == 0) {
        #pragma unroll
        for (int j = 0; j < 8; ++j) xred[w][oct * 8 + j] = xs[j];
    }
    __syncthreads();
    {
        float v = xred[0][tid] + xred[1][tid] + xred[2][tid] + xred[3][tid];
        atomicAdd(accsb + 8192 + tid, v);
    }
    if (w < 2) {
        #pragma unroll
        for (int r = 0; r < 4; ++r) {
            float v = kreg[r];
            v += __shfl_xor(v, 1); v += __shfl_xor(v, 2);
            v += __shfl_xor(v, 4); v += __shfl_xor(v, 8);
            if (l15 == 0) atomicAdd(accsb + 8448 + 16 * (w & 1) + 4 * l4 + r, v);
        }
    }
}

// ---------------------------------------------------------------------------
// k2a: reduce 64 per-block KX partials -> acc
// ---------------------------------------------------------------------------
__global__ __launch_bounds__(256)
void k2a_reduce(const float* __restrict__ pbuf, float* __restrict__ acc)
{
    const int b = blockIdx.x, s = blockIdx.y, cs = blockIdx.z;
    const float* __restrict__ p = pbuf + (size_t)(s*BB + b) * 64 * 8192;
    float* __restrict__ a = acc + (size_t)(s*BB + b) * ACC_STRIDE;
    const int d = threadIdx.x >> 3, c = cs * 32 + (threadIdx.x & 7) * 4;
    f4 v = (f4){0.f, 0.f, 0.f, 0.f};
    for (int j = 0; j < 64; ++j)
        v += *(const f4*)(p + (size_t)j * 8192 + d * 256 + c);
    *(f4*)(a + d * 256 + c) = v;
}

// ---------------------------------------------------------------------------
// k2: finalize per (b,s): mat = KX @ Wv^T + ksum0 (x) bv ; vsum = Wv@xsum + N*bv
// ---------------------------------------------------------------------------
__global__ __launch_bounds__(256, 2)
void k2_finalize(const float* __restrict__ Wv, const float* __restrict__ bv,
                 const float* __restrict__ Wvy, const float* __restrict__ bvy,
                 const float* __restrict__ acc, float* __restrict__ fin)
{
    const int b = blockIdx.x, s = blockIdx.y;
    const float* __restrict__ Wv_ = s ? Wvy : Wv;
    const float* __restrict__ bv_ = s ? bvy : bv;
    const float* __restrict__ a = acc + (size_t)(s*BB + b) * ACC_STRIDE;
    float* __restrict__ f = fin + (size_t)(s*BB + b) * FIN_STRIDE;

    __shared__ float KXt[256][36];
    __shared__ float xsh[256];
    __shared__ float ks0[32];

    const int tid = threadIdx.x;
    for (int d = 0; d < 32; ++d) KXt[tid][d] = a[d*256 + tid];
    xsh[tid] = a[8192 + tid];
    if (tid < 32) { float v = a[8448 + tid]; ks0[tid] = v; f[8448 + tid] = v + EPSF; }
    __syncthreads();

    const int dh = tid >> 7;
    const int c0 = (tid & 127) * 2;
    float macc[16][2];
    #pragma unroll
    for (int i = 0; i < 16; ++i) { macc[i][0]=0.f; macc[i][1]=0.f; }
    float v0 = 0.f, v1 = 0.f;

    for (int k4 = 0; k4 < 256; k4 += 4) {
        float4 wa = *(const float4*)(Wv_ + (size_t)c0*256 + k4);
        float4 wb = *(const float4*)(Wv_ + (size_t)(c0+1)*256 + k4);
        float4 xv = *(const float4*)&xsh[k4];
        v0 += wa.x*xv.x + wa.y*xv.y + wa.z*xv.z + wa.w*xv.w;
        v1 += wb.x*xv.x + wb.y*xv.y + wb.z*xv.z + wb.w*xv.w;
        #pragma unroll
        for (int u = 0; u < 4; ++u) {
            float wau = (u==0)?wa.x:(u==1)?wa.y:(u==2)?wa.z:wa.w;
            float wbu = (u==0)?wb.x:(u==1)?wb.y:(u==2)?wb.z:wb.w;
            #pragma unroll
            for (int i4 = 0; i4 < 16; i4 += 4) {
                float4 kxv = *(const float4*)&KXt[k4+u][dh*16 + i4];
                macc[i4+0][0] += kxv.x*wau; macc[i4+0][1] += kxv.x*wbu;
                macc[i4+1][0] += kxv.y*wau; macc[i4+1][1] += kxv.y*wbu;
                macc[i4+2][0] += kxv.z*wau; macc[i4+2][1] += kxv.z*wbu;
                macc[i4+3][0] += kxv.w*wau; macc[i4+3][1] += kxv.w*wbu;
            }
        }
    }
    float bvc0 = bv_[c0], bvc1 = bv_[c0+1];
    if (dh == 0) {
        f[8192 + c0]     = v0 + (float)NN * bvc0;
        f[8192 + c0 + 1] = v1 + (float)NN * bvc1;
    }
    #pragma unroll
    for (int i = 0; i < 16; ++i) {
        int d = dh*16 + i;
        f[d*256 + c0]     = macc[i][0] + ks0[d]*bvc0;
        f[d*256 + c0 + 1] = macc[i][1] + ks0[d]*bvc1;
    }
}

// ---------------------------------------------------------------------------
// k3: MFMA output kernel. Per block: batch b, 64 positions, both streams.
//   Atb[r][k] bf16 (r=128: 64 x-rows + 64 y-rows; k=64: mat|maty), XOR-swizzled.
//   Msb[c][k] bf16 (Ms^T), XOR-swizzled.
//   D[c][r] = sum_k Msb[c][k]*Atb[r][k]; epilogue adds sv[r]*vs[str][c];
//   C-layout gives lane 4 consecutive c -> float4 stores.
// ---------------------------------------------------------------------------
__global__ __launch_bounds__(512, 2)
void k3_output(const unsigned short* __restrict__ qbuf16, const float* __restrict__ fin,
               const float* __restrict__ g_gamma, const float* __restrict__ g_gammay,
               const float* __restrict__ g_gammacx, const float* __restrict__ g_gammacy,
               const float* __restrict__ g_wx1, const float* __restrict__ g_wx2,
               const float* __restrict__ g_wy1, const float* __restrict__ g_wy2,
               float* __restrict__ out)
{
    const int b = blockIdx.y;
    const int p0 = blockIdx.x * 64;
    const float* __restrict__ fx_ = fin + (size_t)(0*BB + b) * FIN_STRIDE;
    const float* __restrict__ fy_ = fin + (size_t)(1*BB + b) * FIN_STRIDE;

    __shared__ unsigned short Msb[256 * 64];   // 32 KB
    __shared__ unsigned short Atb[128 * 64];   // 16 KB
    __shared__ float vs[2][256];
    __shared__ float sv[128];
    __shared__ float ksl[2][32];

    const int tid = threadIdx.x;

    // phase 0: ksl (needed by coef phase) + vs (needed post-MFMA)
    if (tid < 64) ksl[tid >> 5][tid & 31] = ((tid < 32) ? fx_ : fy_)[8448 + (tid & 31)];
    vs[tid >> 8][tid & 255] = ((tid < 256) ? fx_ : fy_)[8192 + (tid & 255)];
    __syncthreads();

    // phase A1: Msb fill (all 512 threads, 4 tasks each). task=(c,kg): k=kg*8..+7
    #pragma unroll
    for (int i = 0; i < 4; ++i) {
        int task = tid * 4 + i;
        int c = task >> 3, kg = task & 7;
        const float* __restrict__ fp = ((kg < 4) ? fx_ : fy_) + (size_t)((kg & 3) * 8) * 256 + c;
        uint4 pk;
        pk.x = bfp(fp[0])    | (bfp(fp[256])  << 16);
        pk.y = bfp(fp[512])  | (bfp(fp[768])  << 16);
        pk.z = bfp(fp[1024]) | (bfp(fp[1280]) << 16);
        pk.w = bfp(fp[1536]) | (bfp(fp[1792]) << 16);
        unsigned off = (unsigned)(c * 128 + kg * 16) ^ (unsigned)((c & 7) << 4);
        *(uint4*)((char*)Msb + off) = pk;
    }

    // phase A2: coef + Atb rows (tid < 128)
    if (tid < 128) {
        const int str = tid >> 6;
        const int p = p0 + (tid & 63);
        const uint4* __restrict__ qp = (const uint4*)(qbuf16 + ((size_t)(str*BB + b) * NN + p) * DD);
        float q[32];
        float ss = 0.f;
        #pragma unroll
        for (int m = 0; m < 4; ++m) {
            uint4 u = qp[m];
            unsigned uu[4] = {u.x, u.y, u.z, u.w};
            #pragma unroll
            for (int j = 0; j < 4; ++j) {
                float lo = bf2f(uu[j] & 0xFFFFu), hi = bf2f(uu[j] >> 16);
                q[m*8 + 2*j] = lo; q[m*8 + 2*j + 1] = hi;
                ss += lo*lo + hi*hi;
            }
        }
        float qn = rsqrtf(ss);
        float dK = 0.f, dKy = 0.f;
        #pragma unroll
        for (int d = 0; d < 32; ++d) { dK += q[d]*ksl[0][d]; dKy += q[d]*ksl[1][d]; }
        dK *= qn; dKy *= qn;
        float clo, chi, svr;
        if (str == 0) {
            float t1 = 1.f / ((float)NN + dK);
            float t2 = 1.f / ((float)NN + dKy);
            float a1c = g_gamma[0]   * g_wx1[0] * t1;
            float a2c = g_gammacx[0] * g_wx2[0] * t2;
            clo = a1c * qn; chi = a2c * qn; svr = a1c + a2c;
        } else {
            float ty1 = 1.f / ((float)NN + dKy);
            float ty2 = 1.f / ((float)NN + dK);
            float b1c = g_gammay[0]  * g_wy1[0] * ty1;
            float b2c = g_gammacy[0] * g_wy2[0] * ty2;
            clo = b2c * qn; chi = b1c * qn; svr = b1c + b2c;
        }
        sv[tid] = svr;
        // Atb row: k<32 -> clo*q[k] (mat half); k>=32 -> chi*q[k-32] (maty half)
        #pragma unroll
        for (int g = 0; g < 8; ++g) {
            float m0 = (g < 4) ? clo : chi;
            const float* qq = q + (g & 3) * 8;
            uint4 pk;
            pk.x = bfp(m0*qq[0]) | (bfp(m0*qq[1]) << 16);
            pk.y = bfp(m0*qq[2]) | (bfp(m0*qq[3]) << 16);
            pk.z = bfp(m0*qq[4]) | (bfp(m0*qq[5]) << 16);
            pk.w = bfp(m0*qq[6]) | (bfp(m0*qq[7]) << 16);
            unsigned off = (unsigned)(tid * 128 + g * 16) ^ (unsigned)((tid & 7) << 4);
            *(uint4*)((char*)Atb + off) = pk;
        }
    }
    __syncthreads();   // Msb + Atb + sv ready

    // ---- MFMA: wave w -> rtile w; 16 ctiles x 2 ksteps
    const int w = tid >> 6, lane = tid & 63;
    const int l15 = lane & 15, l4 = lane >> 4;
    const int r = w * 16 + l15;
    f4 accv[16];
    #pragma unroll
    for (int ct = 0; ct < 16; ++ct) accv[ct] = (f4){0.f, 0.f, 0.f, 0.f};

    #pragma unroll
    for (int kstep = 0; kstep < 2; ++kstep) {
        unsigned boff = (unsigned)(r * 128 + kstep * 64 + l4 * 16) ^ (unsigned)((r & 7) << 4);
        bh8 bfr = *(const bh8*)((const char*)Atb + boff);
        #pragma unroll
        for (int ct = 0; ct < 16; ++ct) {
            int c = ct * 16 + l15;
            unsigned aoff = (unsigned)(c * 128 + kstep * 64 + l4 * 16) ^ (unsigned)((c & 7) << 4);
            bh8 afr = *(const bh8*)((const char*)Msb + aoff);
            accv[ct] = MFMA16(afr, bfr, accv[ct], 0, 0, 0);
        }
    }

    // ---- epilogue: add sv[r]*vs and store float4 (lane holds 4 consecutive c)
    const int str = w >> 2;
    const int prow = (w & 3) * 16 + l15;
    float* __restrict__ op = out + (size_t)str * BB * NN * CC + ((size_t)b * NN + p0 + prow) * CC;
    const float svr = sv[r];
    #pragma unroll
    for (int ct = 0; ct < 16; ++ct) {
        int c0 = ct * 16 + 4 * l4;
        float4 vsv = *(const float4*)&vs[str][c0];
        float4 o = make_float4(accv[ct][0] + svr*vsv.x, accv[ct][1] + svr*vsv.y,
                               accv[ct][2] + svr*vsv.z, accv[ct][3] + svr*vsv.w);
        *(float4*)(op + c0) = o;
    }
}

extern "C" void kernel_launch(void* const* d_in, const int* in_sizes, int n_in,
                              void* d_out, int out_size, void* d_ws, size_t ws_size,
                              hipStream_t stream)
{
    (void)in_sizes; (void)n_in; (void)out_size; (void)ws_size;
    const float* x   = (const float*)d_in[0];
    const float* y   = (const float*)d_in[1];
    const float* Wq  = (const float*)d_in[2];
    const float* bq  = (const float*)d_in[3];
    const float* Wk  = (const float*)d_in[4];
    const float* bk  = (const float*)d_in[5];
    const float* Wv  = (const float*)d_in[6];
    const float* bv  = (const float*)d_in[7];
    const float* Wqy = (const float*)d_in[8];
    const float* bqy = (const float*)d_in[9];
    const float* Wky = (const float*)d_in[10];
    const float* bky = (const float*)d_in[11];
    const float* Wvy = (const float*)d_in[12];
    const float* bvy = (const float*)d_in[13];

    float* ws   = (float*)d_ws;
    unsigned short* qbuf16 = (unsigned short*)ws;
    float* acc  = ws + ACC_OFF;
    float* fin  = ws + FIN_OFF;
    unsigned short* wbf = (unsigned short*)(ws + WBF_OFF);
    float* pbuf = (float*)d_out;    // scratch: fully consumed by k2a before k3 overwrites

    k0_cvt<<<128, 256, 0, stream>>>(Wk, Wq, Wky, Wqy, wbf);
    hipMemsetAsync(acc, 0, ACC_FLOATS * sizeof(float), stream);

    k1_proj<<<dim3(64, BB, 2), 256, 0, stream>>>(x, y, wbf, bk, bq, bky, bqy, qbuf16, acc, pbuf);
    k2a_reduce<<<dim3(BB, 2, 8), 256, 0, stream>>>(pbuf, acc);
    k2_finalize<<<dim3(BB, 2), 256, 0, stream>>>(Wv, bv, Wvy, bvy, acc, fin);
    k3_output<<<dim3(NN/64, BB), 512, 0, stream>>>(qbuf16, fin,
        (const float*)d_in[14], (const float*)d_in[15], (const float*)d_in[16], (const float*)d_in[17],
        (const float*)d_in[18], (const float*)d_in[19], (const float*)d_in[20], (const float*)d_in[21],
        (float*)d_out);
}